// Round 3
// baseline (239.066 us; speedup 1.0000x reference)
//
#include <hip/hip_runtime.h>
#include <math.h>

// Shapes fixed by the reference's setup_inputs()
#define B_ 4
#define N_ 8192
#define M_ 8192
#define O_ 32
#define E_ 128
#define F_ 128
#define K_ 8

#define LOG_HALF_F (-0.6931471805599453f)
#define EXPM1_GUARD_F 1e-7f

// One 128-thread block per (b, m) pair.
__global__ __launch_bounds__(128) void n3agg_kernel(
    const float* __restrict__ x,        // (B,N,F)
    const float* __restrict__ xe,       // (B,N,E)
    const float* __restrict__ ye,       // (B,M,E)
    const float* __restrict__ log_temp, // (1,)
    const int*   __restrict__ I,        // (B,M,O)
    float*       __restrict__ out)      // (B,M,F,K)
{
    __shared__ int   s_idx[O_];
    __shared__ float s_logits[O_];
    __shared__ float s_W[K_ * O_];   // [k][o] layout: conflict-free writes, broadcast reads

    const int t  = threadIdx.x;
    const int bm = blockIdx.x;           // b*M + m
    const int b  = bm >> 13;             // / M_ (M_ = 8192)

    const float inv_temp = 1.0f / expf(log_temp[0]);

    if (t < O_) s_idx[t] = I[(size_t)bm * O_ + t];
    __syncthreads();

    // ---- distance phase: 32 groups x 4 lanes, each lane covers 32 of E=128 ----
    {
        const int g = t >> 2;   // which candidate o
        const int l = t & 3;    // lane within group
        const float4* yrow = (const float4*)(ye + (size_t)bm * E_ + l * 32);
        const float4* xrow = (const float4*)(xe + ((size_t)b * N_ + s_idx[g]) * E_ + l * 32);
        float acc = 0.f;
        #pragma unroll
        for (int j = 0; j < 8; ++j) {
            float4 yv = yrow[j];
            float4 xv = xrow[j];
            float d0 = xv.x - yv.x, d1 = xv.y - yv.y;
            float d2 = xv.z - yv.z, d3 = xv.w - yv.w;
            acc += d0 * d0 + d1 * d1 + d2 * d2 + d3 * d3;
        }
        acc += __shfl_xor(acc, 1);
        acc += __shfl_xor(acc, 2);
        if (l == 0) s_logits[g] = -acc * inv_temp;   // D / temperature
    }
    __syncthreads();

    // ---- K-step relaxed top-k softmax: wave 0, lanes 0..31 (one lane per o) ----
    if (t < O_) {
        float logit = s_logits[t];
        #pragma unroll 1
        for (int k = 0; k < K_; ++k) {
            // log_softmax over the 32 lanes
            float mx = logit;
            #pragma unroll
            for (int d = 16; d >= 1; d >>= 1) mx = fmaxf(mx, __shfl_xor(mx, d, 32));
            float sh = logit - mx;
            float ev = expf(sh);
            float sm = ev;
            #pragma unroll
            for (int d = 16; d >= 1; d >>= 1) sm += __shfl_xor(sm, d, 32);
            float w = sh - logf(sm);          // log-prob
            float sample = expf(w);
            s_W[k * O_ + t] = sample;
            // log1mexp(w), matching the reference's guard semantics exactly
            float lm;
            if (w < LOG_HALF_F) lm = log1pf(-sample);                       // log1p(-exp(w))
            else                lm = logf(-expm1f(w) + EXPM1_GUARD_F);
            logit += lm;
        }
    }
    __syncthreads();

    // ---- aggregation: thread t owns f = t, computes all K outputs ----
    {
        const int f = t;
        const float* xb = x + (size_t)b * N_ * F_ + f;
        float acc[K_];
        #pragma unroll
        for (int k = 0; k < K_; ++k) acc[k] = 0.f;
        #pragma unroll 4
        for (int o = 0; o < O_; ++o) {
            const float xv = xb[(size_t)s_idx[o] * F_];
            #pragma unroll
            for (int k = 0; k < K_; ++k) acc[k] += xv * s_W[k * O_ + o];
        }
        float* orow = out + ((size_t)bm * F_ + f) * K_;
        ((float4*)orow)[0] = make_float4(acc[0], acc[1], acc[2], acc[3]);
        ((float4*)orow)[1] = make_float4(acc[4], acc[5], acc[6], acc[7]);
    }
}

extern "C" void kernel_launch(void* const* d_in, const int* in_sizes, int n_in,
                              void* d_out, int out_size, void* d_ws, size_t ws_size,
                              hipStream_t stream) {
    const float* x        = (const float*)d_in[0];
    const float* xe       = (const float*)d_in[1];
    const float* ye       = (const float*)d_in[2];
    const float* log_temp = (const float*)d_in[3];
    const int*   I        = (const int*)d_in[4];
    float* out = (float*)d_out;

    dim3 grid(B_ * M_);
    dim3 block(128);
    hipLaunchKernelGGL(n3agg_kernel, grid, block, 0, stream,
                       x, xe, ye, log_temp, I, out);
}

// Round 4
// 224.386 us; speedup vs baseline: 1.0654x; 1.0654x over previous
//
#include <hip/hip_runtime.h>
#include <math.h>

// Shapes fixed by the reference's setup_inputs()
#define B_ 4
#define N_ 8192
#define M_ 8192
#define O_ 32
#define E_ 128
#define F_ 128
#define K_ 8

#define LOG_HALF_F (-0.6931471805599453f)
#define GUARD_F 1e-7f

// One 128-thread block (2 waves) per (b, m) pair.
// __launch_bounds__(128, 8): 8 waves/EU -> 16 blocks/CU, caps VGPR at 64.
__global__ __launch_bounds__(128, 8) void n3agg_kernel(
    const float* __restrict__ x,        // (B,N,F)
    const float* __restrict__ xe,       // (B,N,E)
    const float* __restrict__ ye,       // (B,M,E)
    const float* __restrict__ log_temp, // (1,)
    const int*   __restrict__ I,        // (B,M,O)
    float*       __restrict__ out)      // (B,M,F,K)
{
    __shared__ int   s_idx[O_];
    __shared__ float s_logits[O_];
    __shared__ float s_W[O_ * K_];   // [o][k]: contiguous 8 floats per o -> 2x ds_read_b128 broadcast

    const int t  = threadIdx.x;
    const int bm = blockIdx.x;           // b*M + m
    const int b  = bm >> 13;             // / M_

    const float inv_temp = 1.0f / expf(log_temp[0]);

    if (t < O_) s_idx[t] = I[(size_t)bm * O_ + t];
    __syncthreads();

    // ---- distance phase: 32 groups x 4 lanes, each lane covers 32 of E=128 ----
    {
        const int g = t >> 2;   // candidate o
        const int l = t & 3;    // lane within group
        const float4* yrow = (const float4*)(ye + (size_t)bm * E_ + l * 32);
        const float4* xrow = (const float4*)(xe + ((size_t)b * N_ + s_idx[g]) * E_ + l * 32);
        float acc = 0.f;
        #pragma unroll
        for (int j = 0; j < 8; ++j) {
            float4 yv = yrow[j];
            float4 xv = xrow[j];
            float d0 = xv.x - yv.x, d1 = xv.y - yv.y;
            float d2 = xv.z - yv.z, d3 = xv.w - yv.w;
            acc += d0 * d0 + d1 * d1 + d2 * d2 + d3 * d3;
        }
        acc += __shfl_xor(acc, 1);
        acc += __shfl_xor(acc, 2);
        if (l == 0) s_logits[g] = -acc * inv_temp;   // D / temperature
    }
    __syncthreads();   // s_logits ready

    // ---- prefetch ALL 32 gathered x values into registers (thread t owns f=t).
    // Addresses depend only on s_idx; latency hides under the softmax below.
    const float* xb = x + (size_t)b * (N_ * F_) + t;
    float xv[O_];
    #pragma unroll
    for (int o = 0; o < O_; ++o) {
        xv[o] = xb[(size_t)(s_idx[o] * F_)];
    }

    // ---- K-step relaxed top-k softmax: wave 0, lanes 0..31 (one lane per o) ----
    if (t < O_) {
        float logit = s_logits[t];
        float wloc[K_];
        #pragma unroll
        for (int k = 0; k < K_; ++k) {
            // log_softmax over the 32 lanes
            float mx = logit;
            #pragma unroll
            for (int d = 16; d >= 1; d >>= 1) mx = fmaxf(mx, __shfl_xor(mx, d, 32));
            float sh = logit - mx;
            float ev = __expf(sh);
            float sm = ev;
            #pragma unroll
            for (int d = 16; d >= 1; d >>= 1) sm += __shfl_xor(sm, d, 32);
            float w = sh - logf(sm);         // libm logf: absolute accuracy near sm~1 matters
            float sample = __expf(w);
            wloc[k] = sample;
            // log1mexp(w), matching the reference's branch + guard semantics:
            //  w <  log(0.5): log1p(-exp(w))  == log(1 - sample), no cancellation
            //  w >= log(0.5): log(-expm1(w) + 1e-7); expm1 via deg-7 Taylor
            //                 (relative-accurate on (log0.5, 0], the only range used)
            float p = w * (1.0f + w * (0.5f + w * (0.16666667f + w * (4.1666667e-2f
                    + w * (8.3333333e-3f + w * (1.3888889e-3f + w * 1.9841270e-4f))))));
            float arg = (w < LOG_HALF_F) ? (1.0f - sample) : (GUARD_F - p);
            logit += __logf(arg);
        }
        // write W row [o=t][k=0..7] as two float4s
        ((float4*)&s_W[t * K_])[0] = make_float4(wloc[0], wloc[1], wloc[2], wloc[3]);
        ((float4*)&s_W[t * K_])[1] = make_float4(wloc[4], wloc[5], wloc[6], wloc[7]);
    }
    __syncthreads();   // s_W ready (also drains the xv prefetch)

    // ---- aggregation: thread t owns f = t, all K outputs from registers + W broadcasts ----
    {
        float acc[K_];
        #pragma unroll
        for (int k = 0; k < K_; ++k) acc[k] = 0.f;
        #pragma unroll
        for (int o = 0; o < O_; ++o) {
            const float4 w0 = ((const float4*)&s_W[o * K_])[0];
            const float4 w1 = ((const float4*)&s_W[o * K_])[1];
            const float xvo = xv[o];
            acc[0] = fmaf(xvo, w0.x, acc[0]);
            acc[1] = fmaf(xvo, w0.y, acc[1]);
            acc[2] = fmaf(xvo, w0.z, acc[2]);
            acc[3] = fmaf(xvo, w0.w, acc[3]);
            acc[4] = fmaf(xvo, w1.x, acc[4]);
            acc[5] = fmaf(xvo, w1.y, acc[5]);
            acc[6] = fmaf(xvo, w1.z, acc[6]);
            acc[7] = fmaf(xvo, w1.w, acc[7]);
        }
        float* orow = out + ((size_t)bm * F_ + t) * K_;
        ((float4*)orow)[0] = make_float4(acc[0], acc[1], acc[2], acc[3]);
        ((float4*)orow)[1] = make_float4(acc[4], acc[5], acc[6], acc[7]);
    }
}

extern "C" void kernel_launch(void* const* d_in, const int* in_sizes, int n_in,
                              void* d_out, int out_size, void* d_ws, size_t ws_size,
                              hipStream_t stream) {
    const float* x        = (const float*)d_in[0];
    const float* xe       = (const float*)d_in[1];
    const float* ye       = (const float*)d_in[2];
    const float* log_temp = (const float*)d_in[3];
    const int*   I        = (const int*)d_in[4];
    float* out = (float*)d_out;

    dim3 grid(B_ * M_);
    dim3 block(128);
    hipLaunchKernelGGL(n3agg_kernel, grid, block, 0, stream,
                       x, xe, ye, log_temp, I, out);
}

// Round 5
// 155.405 us; speedup vs baseline: 1.5383x; 1.4439x over previous
//
#include <hip/hip_runtime.h>
#include <math.h>

// Shapes fixed by the reference's setup_inputs()
#define B_ 4
#define N_ 8192
#define M_ 8192
#define O_ 32
#define E_ 128
#define F_ 128
#define K_ 8

#define LOG_HALF_F (-0.6931471805599453f)
#define GUARD_F 1e-7f

typedef float f4v __attribute__((ext_vector_type(4)));

// One 128-thread block (2 waves) per (b, m) pair.
// __launch_bounds__(128, 6): 6 waves/EU -> 12 blocks/CU, VGPR cap ~84
// (room for the 32 pinned prefetch registers without spill).
__global__ __launch_bounds__(128, 6) void n3agg_kernel(
    const float* __restrict__ x,        // (B,N,F)
    const float* __restrict__ xe,       // (B,N,E)
    const float* __restrict__ ye,       // (B,M,E)
    const float* __restrict__ log_temp, // (1,)
    const int*   __restrict__ I,        // (B,M,O)
    float*       __restrict__ out)      // (B,M,F,K)
{
    __shared__ float s_logits[O_];
    __shared__ float s_W[O_ * K_];   // [o][k]: 2x ds_read_b128 broadcast per o

    const int t  = threadIdx.x;
    const int bm = blockIdx.x;           // b*M + m
    const int b  = bm >> 13;             // / M_

    const float inv_temp = 1.0f / expf(log_temp[0]);

    // ---- distance phase: 32 groups x 4 lanes, CONTIGUOUS per-group access ----
    // lane l of group g reads float4 at element offset (j*4+l)*4:
    // the 4 lanes cover 64 contiguous bytes per j -> each wave-load touches
    // 16 dense cache lines (vs 64 sparse ones before), each line exactly once.
    {
        const int g = t >> 2;   // candidate o (0..31 across the 2 waves)
        const int l = t & 3;    // lane within group
        const int idxg = I[(size_t)bm * O_ + g];          // coalesced, 4 lanes/value
        const float4* yrow = (const float4*)(ye + (size_t)bm * E_);
        const float4* xrow = (const float4*)(xe + ((size_t)b * N_ + idxg) * E_);
        float acc = 0.f;
        #pragma unroll
        for (int j = 0; j < 8; ++j) {
            float4 yv = yrow[j * 4 + l];
            float4 xv = xrow[j * 4 + l];
            float d0 = xv.x - yv.x, d1 = xv.y - yv.y;
            float d2 = xv.z - yv.z, d3 = xv.w - yv.w;
            acc += d0 * d0 + d1 * d1 + d2 * d2 + d3 * d3;
        }
        acc += __shfl_xor(acc, 1);
        acc += __shfl_xor(acc, 2);
        if (l == 0) s_logits[g] = -acc * inv_temp;   // D / temperature
    }

    // ---- prefetch ALL 32 gathered x values (thread t owns f=t). ----
    // Irow is block-uniform -> scalar (SGPR) loads. asm pins force the loads
    // to materialize HERE so the gather latency hides under the softmax
    // (round 4: compiler sank these loads, defeating the prefetch).
    const int* Irow = I + (size_t)bm * O_;
    const float* xb = x + (size_t)b * (N_ * F_) + t;
    float xv[O_];
    #pragma unroll
    for (int o = 0; o < O_; ++o) {
        xv[o] = xb[(size_t)(Irow[o] * F_)];
    }
    #pragma unroll
    for (int o = 0; o < O_; ++o) {
        asm volatile("" : "+v"(xv[o]));   // keep live across softmax, no code
    }

    __syncthreads();   // s_logits ready

    // ---- K-step relaxed top-k softmax: wave 0, lanes 0..31 (one lane per o) ----
    if (t < O_) {
        float logit = s_logits[t];
        float wloc[K_];
        #pragma unroll
        for (int k = 0; k < K_; ++k) {
            float mx = logit;
            #pragma unroll
            for (int d = 16; d >= 1; d >>= 1) mx = fmaxf(mx, __shfl_xor(mx, d, 32));
            float sh = logit - mx;
            float ev = __expf(sh);
            float sm = ev;
            #pragma unroll
            for (int d = 16; d >= 1; d >>= 1) sm += __shfl_xor(sm, d, 32);
            float w = sh - logf(sm);         // libm logf: absolute accuracy near sm~1
            float sample = __expf(w);
            wloc[k] = sample;
            // log1mexp(w), reference branch + guard semantics:
            //  w <  log(0.5): log1p(-exp(w)) == log(1 - sample), no cancellation
            //  w >= log(0.5): log(-expm1(w) + 1e-7), expm1 via deg-7 Taylor
            float p = w * (1.0f + w * (0.5f + w * (0.16666667f + w * (4.1666667e-2f
                    + w * (8.3333333e-3f + w * (1.3888889e-3f + w * 1.9841270e-4f))))));
            float arg = (w < LOG_HALF_F) ? (1.0f - sample) : (GUARD_F - p);
            logit += __logf(arg);
        }
        ((float4*)&s_W[t * K_])[0] = make_float4(wloc[0], wloc[1], wloc[2], wloc[3]);
        ((float4*)&s_W[t * K_])[1] = make_float4(wloc[4], wloc[5], wloc[6], wloc[7]);
    }
    __syncthreads();   // s_W ready

    // ---- aggregation: thread t owns f = t; W via LDS broadcast, x from regs ----
    {
        float acc[K_];
        #pragma unroll
        for (int k = 0; k < K_; ++k) acc[k] = 0.f;
        #pragma unroll
        for (int o = 0; o < O_; ++o) {
            const float4 w0 = ((const float4*)&s_W[o * K_])[0];
            const float4 w1 = ((const float4*)&s_W[o * K_])[1];
            const float xvo = xv[o];
            acc[0] = fmaf(xvo, w0.x, acc[0]);
            acc[1] = fmaf(xvo, w0.y, acc[1]);
            acc[2] = fmaf(xvo, w0.z, acc[2]);
            acc[3] = fmaf(xvo, w0.w, acc[3]);
            acc[4] = fmaf(xvo, w1.x, acc[4]);
            acc[5] = fmaf(xvo, w1.y, acc[5]);
            acc[6] = fmaf(xvo, w1.z, acc[6]);
            acc[7] = fmaf(xvo, w1.w, acc[7]);
        }
        // Output is write-once, never re-read: nontemporal keeps it out of L2
        // so the gather working set (x/xe rows) stays cached.
        float* orow = out + ((size_t)bm * F_ + t) * K_;
        f4v o0 = {acc[0], acc[1], acc[2], acc[3]};
        f4v o1 = {acc[4], acc[5], acc[6], acc[7]};
        __builtin_nontemporal_store(o0, (f4v*)orow);
        __builtin_nontemporal_store(o1, (f4v*)(orow + 4));
    }
}

extern "C" void kernel_launch(void* const* d_in, const int* in_sizes, int n_in,
                              void* d_out, int out_size, void* d_ws, size_t ws_size,
                              hipStream_t stream) {
    const float* x        = (const float*)d_in[0];
    const float* xe       = (const float*)d_in[1];
    const float* ye       = (const float*)d_in[2];
    const float* log_temp = (const float*)d_in[3];
    const int*   I        = (const int*)d_in[4];
    float* out = (float*)d_out;

    dim3 grid(B_ * M_);
    dim3 block(128);
    hipLaunchKernelGGL(n3agg_kernel, grid, block, 0, stream,
                       x, xe, ye, log_temp, I, out);
}